// Round 10
// baseline (271.456 us; speedup 1.0000x reference)
//
#include <hip/hip_runtime.h>
#include <math.h>

// Problem: B=64, R=20, L=1024, D=2048 fp32.  out[b,l] = max_r <region[b,r,:], word[b,l,:]>
// Memory-bound: 548 MB mandatory -> ~84us @ 6.6TB/s measured-achievable.
//
// Round-10 = round-8 inner loop, 4x fewer blocks per batch.
//  - Rounds 2/5/8 plateau at ~144us across three stage schedules -> scheduling
//    exhausted. Remaining gap candidate: region RE-STAGING. 64 blocks/batch x
//    160KB = 671 MB extra reads; words streaming through the 4MB per-XCD L2
//    evict region lines between desynced re-reads -> large HBM fraction.
//  - Fix: TPB=1024 (16 waves, WPW=4) -> 64 words/block -> 16 blocks/batch ->
//    restage bound drops 671 -> 168 MB. Inner chunk loop unchanged.
//  - acc stays 80 regs/thread; total ~120 VGPR <= 128 -> 16 waves/CU kept.
//  - NO register word-prefetch (rounds 6/9: +32 VGPR crosses the 128 cliff,
//    occupancy halves -> 230-270us). Words load at point of use.
//  - no min-waves launch bound (rounds 3/4: VGPR caps spill the 80-reg acc).
#define NREG  20
#define LWORDS 1024
#define DDIM  2048
#define DK    256                   // D-chunk: 20*256*4B = 20 KB per buffer
#define NCHUNK (DDIM / DK)          // 8
#define NWAVE 16
#define TPB   (NWAVE * 64)          // 1024
#define WPW   4                     // words per wave
#define WORDS_PER_BLOCK (NWAVE * WPW)   // 64

// async global->LDS, 16B per lane; dst must be wave-uniform (HW adds lane*16)
__device__ __forceinline__ void gload_lds16(const float* src, float* dst) {
    __builtin_amdgcn_global_load_lds(
        (const __attribute__((address_space(1))) void*)src,
        (__attribute__((address_space(3))) void*)dst,
        16, 0, 0);
}

// DPP full-wave (64-lane) sum; result valid in lane 63.
template <int CTRL>
__device__ __forceinline__ float dpp_add_f32(float v) {
    int s = __builtin_amdgcn_update_dpp(0, __float_as_int(v), CTRL, 0xf, 0xf, true);
    return v + __int_as_float(s);
}
__device__ __forceinline__ float wave_sum64(float v) {
    v = dpp_add_f32<0x111>(v);  // row_shr:1
    v = dpp_add_f32<0x112>(v);  // row_shr:2
    v = dpp_add_f32<0x114>(v);  // row_shr:4
    v = dpp_add_f32<0x118>(v);  // row_shr:8
    v = dpp_add_f32<0x142>(v);  // row_bcast:15
    v = dpp_add_f32<0x143>(v);  // row_bcast:31 -> lane 63 = total
    return v;
}

__global__ __launch_bounds__(TPB)
void score_max_kernel(const float* __restrict__ in0,   // (B*20, D) regions
                      const float* __restrict__ in1,   // (B, L, D) words
                      float* __restrict__ out) {       // (B, 1, L)
    __shared__ float reg_lds[2][NREG * DK];            // 40 KB double buffer

    const int bid  = blockIdx.x;
    // bid = t*64 + b: batch b always lands on XCD (b%8) -> regions L2-resident.
    const int b    = bid & 63;
    const int t    = bid >> 6;                          // word tile 0..15
    const int tid  = threadIdx.x;
    const int wave = tid >> 6;
    const int lane = tid & 63;
    const int l0   = t * WORDS_PER_BLOCK + wave * WPW;

    const float* regbase = in0 + (size_t)b * NREG * DDIM;
    const float* wordp   = in1 + ((size_t)b * LWORDS + l0) * DDIM + lane * 4;

    // stage regions[0..19][c*DK .. +DK) into reg_lds[bufsel]:
    // waves 0..15 stage row=wave; waves 0..3 also stage row 16+wave.
    auto stage = [&](int bufsel, int c) {
        {
            const int r = wave;
            gload_lds16(regbase + (size_t)r * DDIM + c * DK + lane * 4,
                        &reg_lds[bufsel][r * DK]);
        }
        if (wave < NREG - NWAVE) {
            const int r = NWAVE + wave;
            gload_lds16(regbase + (size_t)r * DDIM + c * DK + lane * 4,
                        &reg_lds[bufsel][r * DK]);
        }
    };

    float acc[NREG][WPW];
    #pragma unroll
    for (int r = 0; r < NREG; ++r)
        #pragma unroll
        for (int w = 0; w < WPW; ++w) acc[r][w] = 0.0f;

    stage(0, 0);
    int buf = 0;
    for (int c = 0; c < NCHUNK; ++c) {
        // barrier: drains stage(c) (issued last chunk, completed under FMAs)
        // and guarantees all waves finished reading reg_lds[buf^1].
        __syncthreads();

        // ---- word loads FIRST: oldest in the vmcnt queue ----
        const float* wp = wordp + c * DK;
        const float4 wv0 = *reinterpret_cast<const float4*>(wp);
        const float4 wv1 = *reinterpret_cast<const float4*>(wp + DDIM);
        const float4 wv2 = *reinterpret_cast<const float4*>(wp + 2 * (size_t)DDIM);
        const float4 wv3 = *reinterpret_cast<const float4*>(wp + 3 * (size_t)DDIM);
        __builtin_amdgcn_sched_barrier(0);   // pin: stage must issue AFTER words

        if (c + 1 < NCHUNK) stage(buf ^ 1, c + 1);   // stays in flight under FMAs

        const float* rbase = &reg_lds[buf][lane * 4];
        #pragma unroll
        for (int r = 0; r < NREG; ++r) {
            const float4 rv = *reinterpret_cast<const float4*>(rbase + r * DK);
            float a0 = acc[r][0], a1 = acc[r][1], a2 = acc[r][2], a3 = acc[r][3];
            a0 = fmaf(rv.x, wv0.x, a0); a1 = fmaf(rv.x, wv1.x, a1);
            a2 = fmaf(rv.x, wv2.x, a2); a3 = fmaf(rv.x, wv3.x, a3);
            a0 = fmaf(rv.y, wv0.y, a0); a1 = fmaf(rv.y, wv1.y, a1);
            a2 = fmaf(rv.y, wv2.y, a2); a3 = fmaf(rv.y, wv3.y, a3);
            a0 = fmaf(rv.z, wv0.z, a0); a1 = fmaf(rv.z, wv1.z, a1);
            a2 = fmaf(rv.z, wv2.z, a2); a3 = fmaf(rv.z, wv3.z, a3);
            a0 = fmaf(rv.w, wv0.w, a0); a1 = fmaf(rv.w, wv1.w, a1);
            a2 = fmaf(rv.w, wv2.w, a2); a3 = fmaf(rv.w, wv3.w, a3);
            acc[r][0] = a0; acc[r][1] = a1; acc[r][2] = a2; acc[r][3] = a3;
        }
        buf ^= 1;
    }

    // epilogue: DPP wave-sum each acc, max over regions, lane 63 stores.
    #pragma unroll
    for (int w = 0; w < WPW; ++w) {
        float m = -INFINITY;
        #pragma unroll
        for (int r = 0; r < NREG; ++r)
            m = fmaxf(m, wave_sum64(acc[r][w]));
        if (lane == 63) out[(size_t)b * LWORDS + l0 + w] = m;
    }
}

extern "C" void kernel_launch(void* const* d_in, const int* in_sizes, int n_in,
                              void* d_out, int out_size, void* d_ws, size_t ws_size,
                              hipStream_t stream) {
    const float* in0 = (const float*)d_in[0];   // (B*20, D)
    const float* in1 = (const float*)d_in[1];   // (B, L, D)
    float* out = (float*)d_out;                  // (B, 1, L)

    const int grid = 64 * (LWORDS / WORDS_PER_BLOCK);   // 64 * 16 = 1024
    score_max_kernel<<<grid, TPB, 0, stream>>>(in0, in1, out);
}

// Round 11
// 114.220 us; speedup vs baseline: 2.3766x; 2.3766x over previous
//
#include <hip/hip_runtime.h>
#include <math.h>

// Problem: B=64, R=20, L=1024, D=2048 fp32.  out[b,l] = max_r <region[b,r,:], word[b,l,:]>
// Memory-bound: 548 MB mandatory -> ~84us @ 6.6TB/s measured-achievable.
//
// Round-11: MFMA restructure (scalar-FMA structure plateaued at ~144us,
// rounds 2/5/8; root cause = 80-VGPR fp32 accumulator forbids prefetch
// depth and forces a barrier-phased pipeline).
//  - regions -> bf16 MFMA A-fragments staged ONCE per block in LDS (80 KB,
//    no K-chunking, ONE barrier in the whole kernel).
//  - words -> B-fragments streamed DIRECTLY from global (each lane loads its
//    8 contiguous fp32, converts to bf16 in regs; words never touch LDS).
//  - M=20 = tile0 rows 0-15 + tile1 rows 16-19 replicated 4x (duplicate rows
//    are harmless under max; zero-padding would NOT be - scores go negative).
//  - acc = 2 x f32x4 = 8 regs; total ~60-90 VGPR -> no cliff, no spill.
//  - 512 thr (8 waves), 16 words/wave, 128 words/block; grid 512;
//    LDS 80 KB -> 2 blocks/CU = 16 waves/CU; 1-deep B prefetch (named regs).
//  - bid = tb*64 + b keeps batch b on XCD b%8 (regions L2-resident).
#define NREG   20
#define LWORDS 1024
#define DDIM   2048
#define TPB    512
#define KSTEPS (DDIM / 32)          // 64 MFMA K-steps

typedef __attribute__((ext_vector_type(8))) short bf16x8;
typedef __attribute__((ext_vector_type(4))) float f32x4;

// fp32 -> bf16 round-to-nearest-even (inputs are finite; no NaN path needed)
__device__ __forceinline__ ushort f2bf(float f) {
    union { float f; unsigned u; } v; v.f = f;
    const unsigned u = v.u;
    return (ushort)((u + 0x7fffu + ((u >> 16) & 1u)) >> 16);
}

#define CVT8(bq, p0, p1)                                                       \
    do {                                                                       \
        bq[0] = (short)f2bf(p0.x); bq[1] = (short)f2bf(p0.y);                  \
        bq[2] = (short)f2bf(p0.z); bq[3] = (short)f2bf(p0.w);                  \
        bq[4] = (short)f2bf(p1.x); bq[5] = (short)f2bf(p1.y);                  \
        bq[6] = (short)f2bf(p1.z); bq[7] = (short)f2bf(p1.w);                  \
    } while (0)

__global__ __launch_bounds__(TPB)
void score_mfma_kernel(const float* __restrict__ in0,   // (B*20, D) regions
                       const float* __restrict__ in1,   // (B, L, D) words
                       float* __restrict__ out) {       // (B, 1, L)
    // A-fragments, layout chosen so wave reads are lane-sequential 16B
    // (canonical conflict-free ds_read_b128):
    //  lds0[ks*64 + lane]          : rows 0-15,  row=lane&15, k=ks*32+(lane>>4)*8
    //  lds1[ks*16 + (row&3)*4 + kg]: rows 16-19 compact (4-lane broadcast on read)
    __shared__ bf16x8 lds0[KSTEPS * 64];   // 64 KB
    __shared__ bf16x8 lds1[KSTEPS * 16];   // 16 KB

    const int bid  = blockIdx.x;
    const int b    = bid & 63;              // batch -> XCD b%8
    const int tb   = bid >> 6;              // word slab 0..7 (128 words each)
    const int tid  = threadIdx.x;
    const int wave = tid >> 6;
    const int lane = tid & 63;
    const int col  = lane & 15;             // B/D column within 16-word tile
    const int kg   = lane >> 4;             // k-group 0..3 (8 k each)

    const float* reg0 = in0 + (size_t)b * NREG * DDIM;

    // ---- stage regions once: fp32 -> bf16 -> fragment-ordered LDS ----
    #pragma unroll
    for (int i = 0; i < 8; ++i) {           // rows 0-15: 4096 slots
        const int S = i * TPB + tid;
        const int ks = S >> 6, l = S & 63, r = l & 15, g = l >> 4;
        const float* src = reg0 + (size_t)r * DDIM + ks * 32 + g * 8;
        const float4 x = *reinterpret_cast<const float4*>(src);
        const float4 y = *reinterpret_cast<const float4*>(src + 4);
        bf16x8 o; CVT8(o, x, y);
        lds0[S] = o;                         // lane-sequential -> conflict-free
    }
    #pragma unroll
    for (int i = 0; i < 2; ++i) {           // rows 16-19: 1024 slots
        const int S = i * TPB + tid;
        const int ks = S >> 4, r4 = (S >> 2) & 3, g = S & 3;
        const float* src = reg0 + (size_t)(16 + r4) * DDIM + ks * 32 + g * 8;
        const float4 x = *reinterpret_cast<const float4*>(src);
        const float4 y = *reinterpret_cast<const float4*>(src + 4);
        bf16x8 o; CVT8(o, x, y);
        lds1[S] = o;
    }
    __syncthreads();   // the ONLY barrier in the kernel

    // ---- stream words as B-fragments straight from global ----
    // lane (col,kg) owns word (base+col), k = ks*32 + kg*8 .. +8 (32B contig)
    const float* wbase = in1
        + ((size_t)b * LWORDS + tb * 128 + wave * 16 + col) * DDIM + kg * 8;

    f32x4 acc0 = {0.f, 0.f, 0.f, 0.f};      // rows 0-15
    f32x4 acc1 = {0.f, 0.f, 0.f, 0.f};      // rows 16-19 (x4 duplicated)

    float4 pa0 = *reinterpret_cast<const float4*>(wbase);
    float4 pa1 = *reinterpret_cast<const float4*>(wbase + 4);
    float4 pb0, pb1;

    for (int ks = 0; ks < KSTEPS; ks += 2) {
        {   // prefetch ks+1 (ks+1 < 64 always since KSTEPS even)
            const float* p = wbase + (size_t)(ks + 1) * 32;
            pb0 = *reinterpret_cast<const float4*>(p);
            pb1 = *reinterpret_cast<const float4*>(p + 4);
        }
        {   // compute ks with pa
            bf16x8 bq; CVT8(bq, pa0, pa1);
            const bf16x8 a0 = lds0[ks * 64 + lane];
            const bf16x8 a1 = lds1[ks * 16 + (col & 3) * 4 + kg];
            acc0 = __builtin_amdgcn_mfma_f32_16x16x32_bf16(a0, bq, acc0, 0, 0, 0);
            acc1 = __builtin_amdgcn_mfma_f32_16x16x32_bf16(a1, bq, acc1, 0, 0, 0);
        }
        {   // prefetch ks+2 (guarded: reload 0 on last iter, never OOB)
            const size_t off = (ks + 2 < KSTEPS) ? (size_t)(ks + 2) * 32 : 0;
            const float* p = wbase + off;
            pa0 = *reinterpret_cast<const float4*>(p);
            pa1 = *reinterpret_cast<const float4*>(p + 4);
        }
        {   // compute ks+1 with pb
            bf16x8 bq; CVT8(bq, pb0, pb1);
            const bf16x8 a0 = lds0[(ks + 1) * 64 + lane];
            const bf16x8 a1 = lds1[(ks + 1) * 16 + (col & 3) * 4 + kg];
            acc0 = __builtin_amdgcn_mfma_f32_16x16x32_bf16(a0, bq, acc0, 0, 0, 0);
            acc1 = __builtin_amdgcn_mfma_f32_16x16x32_bf16(a1, bq, acc1, 0, 0, 0);
        }
    }

    // ---- max over regions ----
    // D layout (m89-verified): col = lane&15, row = (lane>>4)*4 + reg.
    // Per-lane max over its 8 values, then fold lanes l^16, l^32 ->
    // every lane holds max over all 16 rows of tile0 + the 4 real rows of
    // tile1 (duplicates collapse under max). Lanes 0-15 store.
    float m = fmaxf(fmaxf(fmaxf(acc0[0], acc0[1]), fmaxf(acc0[2], acc0[3])),
                    fmaxf(fmaxf(acc1[0], acc1[1]), fmaxf(acc1[2], acc1[3])));
    m = fmaxf(m, __shfl_xor(m, 16, 64));
    m = fmaxf(m, __shfl_xor(m, 32, 64));
    if (lane < 16)
        out[(size_t)b * LWORDS + tb * 128 + wave * 16 + col] = m;
}

extern "C" void kernel_launch(void* const* d_in, const int* in_sizes, int n_in,
                              void* d_out, int out_size, void* d_ws, size_t ws_size,
                              hipStream_t stream) {
    const float* in0 = (const float*)d_in[0];   // (B*20, D)
    const float* in1 = (const float*)d_in[1];   // (B, L, D)
    float* out = (float*)d_out;                  // (B, 1, L)

    const int grid = 64 * (LWORDS / 128);        // 512 blocks, 2/CU (80KB LDS)
    score_mfma_kernel<<<grid, TPB, 0, stream>>>(in0, in1, out);
}